// Round 4
// baseline (316.688 us; speedup 1.0000x reference)
//
#include <hip/hip_runtime.h>
#include <hip/hip_cooperative_groups.h>

namespace cg = cooperative_groups;

// Problem constants (fixed by the harness / reference setup_inputs()).
constexpr int B = 16384;   // rows of x
constexpr int D = 2048;    // feature dim
constexpr float CLAMP_MIN = 1e-12f;
constexpr float CLAMP_MAX = 1e12f;

constexpr int GRID1  = 1024;   // 4 waves/block -> 4096 waves -> 4 rows/wave.
constexpr int BLOCK1 = 256;
// __launch_bounds__(256, 4): 4 waves/EU min -> VGPR <= 128 -> >=4 blocks/CU
// -> 1024 blocks provably co-resident on 256 CUs (cooperative-launch safe).

// Native clang vector type: legal operand for __builtin_nontemporal_load
// (HIP's float4 is a class type, which the builtin rejects).
typedef float vfloat4 __attribute__((ext_vector_type(4)));

__global__ __launch_bounds__(BLOCK1, 4) void center_loss_coop(
    const float* __restrict__ x,
    const int* __restrict__ labels,
    const float* __restrict__ centers,
    float* __restrict__ partials,   // GRID1 floats in d_ws
    float* __restrict__ out)
{
    const int lane            = threadIdx.x & 63;
    const int wave_in_block   = threadIdx.x >> 6;          // 0..3
    const int waves_per_block = BLOCK1 >> 6;               // 4
    const int global_wave     = blockIdx.x * waves_per_block + wave_in_block;
    const int num_waves       = GRID1 * waves_per_block;   // 4096

    float acc = 0.0f;  // per-wave sum of clipped distances (valid on lane 0)

    for (int row = global_wave; row < B; row += num_waves) {   // 4 iterations
        const int lbl = __builtin_amdgcn_readfirstlane(labels[row]);
        const vfloat4* __restrict__ xr =
            reinterpret_cast<const vfloat4*>(x + (size_t)row * D);
        const vfloat4* __restrict__ cr =
            reinterpret_cast<const vfloat4*>(centers + (size_t)lbl * D);

        float partial = 0.0f;
        #pragma unroll
        for (int j = 0; j < D / 4 / 64; ++j) {  // 8 iterations
            // x is streamed exactly once -> non-temporal, keeps centers hot in L2.
            vfloat4 xv = __builtin_nontemporal_load(&xr[j * 64 + lane]);
            vfloat4 cv = cr[j * 64 + lane];
            float d0 = xv.x - cv.x;
            float d1 = xv.y - cv.y;
            float d2 = xv.z - cv.z;
            float d3 = xv.w - cv.w;
            partial = fmaf(d0, d0,
                      fmaf(d1, d1,
                      fmaf(d2, d2,
                      fmaf(d3, d3, partial))));
        }

        // 64-lane butterfly reduction (wave = 64 on CDNA).
        #pragma unroll
        for (int off = 32; off > 0; off >>= 1)
            partial += __shfl_xor(partial, off, 64);

        if (lane == 0) {
            acc += fminf(fmaxf(partial, CLAMP_MIN), CLAMP_MAX);
        }
    }

    __shared__ float s[4];
    if (lane == 0) s[wave_in_block] = acc;
    __syncthreads();
    if (threadIdx.x == 0)
        partials[blockIdx.x] = (s[0] + s[1]) + (s[2] + s[3]);

    // Grid-wide sync, then block 0 reduces the GRID1 partials.
    cg::this_grid().sync();

    if (blockIdx.x == 0) {
        const int tid = threadIdx.x;
        float v = 0.0f;
        #pragma unroll
        for (int j = 0; j < GRID1 / BLOCK1; ++j)   // 4 values/thread
            v += partials[j * BLOCK1 + tid];

        #pragma unroll
        for (int off = 32; off > 0; off >>= 1)
            v += __shfl_xor(v, off, 64);

        __shared__ float s2[4];
        if ((tid & 63) == 0) s2[tid >> 6] = v;
        __syncthreads();
        if (tid == 0)
            out[0] = ((s2[0] + s2[1]) + (s2[2] + s2[3])) * (1.0f / (float)B);
    }
}

extern "C" void kernel_launch(void* const* d_in, const int* in_sizes, int n_in,
                              void* d_out, int out_size, void* d_ws, size_t ws_size,
                              hipStream_t stream) {
    const float* x        = (const float*)d_in[0];
    const int*   labels   = (const int*)d_in[1];
    const float* centers  = (const float*)d_in[2];
    float*       out      = (float*)d_out;
    float*       partials = (float*)d_ws;     // GRID1 floats of scratch

    void* args[] = {(void*)&x, (void*)&labels, (void*)&centers,
                    (void*)&partials, (void*)&out};
    (void)hipLaunchCooperativeKernel((const void*)center_loss_coop,
                                     dim3(GRID1), dim3(BLOCK1), args, 0, stream);
}

// Round 5
// 193.507 us; speedup vs baseline: 1.6366x; 1.6366x over previous
//
#include <hip/hip_runtime.h>

// Problem constants (fixed by the harness / reference setup_inputs()).
constexpr int B = 16384;   // rows of x
constexpr int D = 2048;    // feature dim
constexpr float CLAMP_MIN = 1e-12f;
constexpr float CLAMP_MAX = 1e12f;

constexpr int GRID1  = 2048;   // 4 waves/block -> 8192 waves -> 2 rows/wave
constexpr int BLOCK1 = 256;

// Native clang vector type (16B loads).
typedef float vfloat4 __attribute__((ext_vector_type(4)));

// Pass 1: one wave (64 lanes) per row, grid-stride over rows.
// All 8 x-loads and 8 center-loads for a row are issued into explicit
// register arrays BEFORE any compute -> ~16 outstanding 16B loads per wave
// (memory-level parallelism is the whole game; R4 showed the serialized
// version is latency-bound at ~0.7 TB/s).
__global__ __launch_bounds__(BLOCK1) void center_loss_pass1(
    const float* __restrict__ x,
    const int* __restrict__ labels,
    const float* __restrict__ centers,
    float* __restrict__ partials)
{
    const int lane            = threadIdx.x & 63;
    const int wave_in_block   = threadIdx.x >> 6;          // 0..3
    const int waves_per_block = BLOCK1 >> 6;               // 4
    const int global_wave     = blockIdx.x * waves_per_block + wave_in_block;
    const int num_waves       = GRID1 * waves_per_block;   // 8192

    float acc = 0.0f;  // per-wave sum of clipped distances (valid on lane 0)

    for (int row = global_wave; row < B; row += num_waves) {   // 2 iterations
        const int lbl = __builtin_amdgcn_readfirstlane(labels[row]);
        const vfloat4* __restrict__ xr =
            reinterpret_cast<const vfloat4*>(x + (size_t)row * D);
        const vfloat4* __restrict__ cr =
            reinterpret_cast<const vfloat4*>(centers + (size_t)lbl * D);

        vfloat4 xv[8], cv[8];
        #pragma unroll
        for (int j = 0; j < 8; ++j) xv[j] = xr[j * 64 + lane];
        #pragma unroll
        for (int j = 0; j < 8; ++j) cv[j] = cr[j * 64 + lane];

        float partial = 0.0f;
        #pragma unroll
        for (int j = 0; j < 8; ++j) {
            float d0 = xv[j].x - cv[j].x;
            float d1 = xv[j].y - cv[j].y;
            float d2 = xv[j].z - cv[j].z;
            float d3 = xv[j].w - cv[j].w;
            partial = fmaf(d0, d0,
                      fmaf(d1, d1,
                      fmaf(d2, d2,
                      fmaf(d3, d3, partial))));
        }

        // 64-lane butterfly reduction (wave = 64 on CDNA).
        #pragma unroll
        for (int off = 32; off > 0; off >>= 1)
            partial += __shfl_xor(partial, off, 64);

        if (lane == 0) {
            acc += fminf(fmaxf(partial, CLAMP_MIN), CLAMP_MAX);
        }
    }

    __shared__ float s[4];
    if (lane == 0) s[wave_in_block] = acc;
    __syncthreads();
    if (threadIdx.x == 0)
        partials[blockIdx.x] = (s[0] + s[1]) + (s[2] + s[3]);
}

// Pass 2: reduce GRID1 partials with a single block, scale by 1/B, write out.
__global__ __launch_bounds__(256) void center_loss_pass2(
    const float* __restrict__ partials,
    float* __restrict__ out)
{
    const int tid = threadIdx.x;
    float v = 0.0f;
    #pragma unroll
    for (int j = 0; j < GRID1 / 256; ++j)      // 8 values per thread
        v += partials[j * 256 + tid];

    #pragma unroll
    for (int off = 32; off > 0; off >>= 1)
        v += __shfl_xor(v, off, 64);

    __shared__ float s[4];
    if ((tid & 63) == 0) s[tid >> 6] = v;
    __syncthreads();
    if (tid == 0)
        out[0] = ((s[0] + s[1]) + (s[2] + s[3])) * (1.0f / (float)B);
}

extern "C" void kernel_launch(void* const* d_in, const int* in_sizes, int n_in,
                              void* d_out, int out_size, void* d_ws, size_t ws_size,
                              hipStream_t stream) {
    const float* x        = (const float*)d_in[0];
    const int*   labels   = (const int*)d_in[1];
    const float* centers  = (const float*)d_in[2];
    float*       out      = (float*)d_out;
    float*       partials = (float*)d_ws;     // GRID1 floats of scratch

    center_loss_pass1<<<GRID1, BLOCK1, 0, stream>>>(x, labels, centers, partials);
    center_loss_pass2<<<1, 256, 0, stream>>>(partials, out);
}